// Round 5
// baseline (1622.453 us; speedup 1.0000x reference)
//
#include <hip/hip_runtime.h>
#include <hip/hip_bf16.h>

// ---------------- problem constants ----------------
#define NB 32
#define T0_ 1000
#define IN_DIM_ 40
#define OUT_DIM_ 512
#define TDNN5_ 1500
#define T1_ 996
#define T2_ 992
#define T3_ 986
#define T4_ 985
#define T5_ 984
#define NCLS_ 1000

#define TM 128
#define TN 64
#define KB 32

typedef __attribute__((ext_vector_type(8))) short short8_t;   // 8 bf16 = 4 VGPR
typedef __attribute__((ext_vector_type(4))) float float4_t;

// async global->LDS, 16B per lane; LDS dest = wave-uniform base + lane*16 (m104/m108)
#define GLDS16(gp, lp) __builtin_amdgcn_global_load_lds( \
    (__attribute__((address_space(1))) void*)(gp), \
    (__attribute__((address_space(3))) void*)(lp), 16, 0, 0)

__device__ __forceinline__ unsigned short f2bf(float f) {   // RNE f32 -> bf16 bits
    unsigned int u = __float_as_uint(f);
    unsigned int r = u + 0x7FFFu + ((u >> 16) & 1u);
    return (unsigned short)(r >> 16);
}
__device__ __forceinline__ float bf2f(unsigned short h) {
    return __uint_as_float((unsigned int)h << 16);
}

// ---------------- prep kernels ----------------

// x [32][40][1000] f32 -> xhi/xlo flat [32][1000*40] bf16 planes (hi + residual)
__global__ __launch_bounds__(256) void xsplit_k(const float* __restrict__ x,
                                                unsigned short* __restrict__ xhi,
                                                unsigned short* __restrict__ xlo) {
    int idx = blockIdx.x * 256 + threadIdx.x;
    if (idx >= NB * T0_ * IN_DIM_) return;
    int i = idx % IN_DIM_;
    int t = (idx / IN_DIM_) % T0_;
    int b = idx / (IN_DIM_ * T0_);
    float v = x[((size_t)b * IN_DIM_ + i) * T0_ + t];
    unsigned short h = f2bf(v);
    xhi[idx] = h;
    xlo[idx] = f2bf(v - bf2f(h));
}

// conv kernel [Co][Ci][W] f32 -> wT_hi/lo [Npad][Kpad] bf16, k = w*Ci+i, zero padded.
// Zero pads guarantee: any garbage A value at k>=K (or row>=N) multiplies a 0 weight.
__global__ __launch_bounds__(256) void wsplit_k(const float* __restrict__ src,
                                                unsigned short* __restrict__ whi,
                                                unsigned short* __restrict__ wlo,
                                                int N, int Npad, int K, int Kpad,
                                                int Ci, int W) {
    long total = (long)Npad * Kpad;
    long idx = (long)blockIdx.x * 256 + threadIdx.x;
    if (idx >= total) return;
    int n = (int)(idx / Kpad);
    int k = (int)(idx % Kpad);
    float v = 0.f;
    if (n < N && k < K) {
        int w = k / Ci, i = k % Ci;
        v = src[((size_t)n * Ci + i) * W + w];
    }
    unsigned short h = f2bf(v);
    whi[idx] = h;
    wlo[idx] = f2bf(v - bf2f(h));
}

__global__ __launch_bounds__(256) void zero_k(float* __restrict__ p, int n) {
    int i = blockIdx.x * 256 + threadIdx.x;
    if (i < n) p[i] = 0.f;
}

// ---------------- split-bf16 MFMA conv-as-GEMM ----------------
// out[b,t,o] = relu(bias[o] + sum_k A[t][k]*Wt[o][k]);  A[t][k] = in[b*inB + (t+rowOff)*Ci + k]
// A,W as hi/lo bf16 planes; fp32 acc via 3 MFMAs (hh, lh, hl); per-product err ~2^-18.
// Staging: global_load_lds dwordx4 (m97 structure, 2-barrier K-loop).
// Grid: 1-D, y-fastest decode -> XCD = bid%8 pins each 64-col weight tile to one XCD
// (B-panel L2-resident; T1 mechanism applied to the actual reuse axis).
// Occupancy: LDS = 24 KiB/block (6 blocks/CU possible); binding constraint is VGPR
// (~110-130 live -> 3 waves/SIMD). launch_bounds(256,3) pins the allocator to that
// operating point (m97's measured ~3 blocks/CU; implicit MFMA/VALU overlap per m114).
// STATS: accumulate per-(b,col) sum/sumsq of relu output into gsum/gsq instead of out.
template <bool STATS>
__global__ __launch_bounds__(256, 3) void conv_mfma(
    const unsigned short* __restrict__ in_hi, const unsigned short* __restrict__ in_lo,
    const unsigned short* __restrict__ w_hi,  const unsigned short* __restrict__ w_lo,
    const float* __restrict__ bias,
    unsigned short* __restrict__ out_hi, unsigned short* __restrict__ out_lo,
    float* __restrict__ gsum, float* __restrict__ gsq,
    int GY, int M, int N, int Kpad, int Ci, int rowOff, long inB, long outB) {

    __shared__ unsigned short As_hi[TM][KB];   // rows of 64B, linear (DMA-compatible)
    __shared__ unsigned short As_lo[TM][KB];
    __shared__ unsigned short Bs_hi[TN][KB];
    __shared__ unsigned short Bs_lo[TN][KB];

    const int tid  = threadIdx.x;
    const int lane = tid & 63;
    const int wav  = tid >> 6;
    const int lr   = lane & 15;
    const int lq   = lane >> 4;

    // y-fastest decode: same-y blocks -> same XCD (GY % 8 == 0)
    const int bid = blockIdx.x;
    const int n0 = (bid % GY) * TN;
    const int rem = bid / GY;
    const int t0 = (rem & 7) * TM;   // GX = 8 for every layer
    const int b  = rem >> 3;

    // per-lane global element offsets for DMA staging (16B = 8 bf16 per lane);
    // lane i -> LDS row base+i/4, chunk i%4 == global row +sr, chunk sc  (linear match)
    const int sr = lane >> 2;            // 0..15
    const int sc = (lane & 3) * 8;       // 0,8,16,24
    const unsigned short* Ah = in_hi + (size_t)b * inB;
    const unsigned short* Al = in_lo + (size_t)b * inB;
    const size_t gA0 = (size_t)(t0 + rowOff + 32 * wav + sr) * Ci + sc;
    const size_t gA1 = (size_t)(t0 + rowOff + 32 * wav + 16 + sr) * Ci + sc;
    const size_t gB  = (size_t)(n0 + 16 * wav + sr) * Kpad + sc;
    // wave-uniform LDS bases (wave w owns As rows [32w,32w+32), Bs rows [16w,16w+16))
    unsigned short* ldsA0h = &As_hi[32 * wav][0];
    unsigned short* ldsA1h = &As_hi[32 * wav + 16][0];
    unsigned short* ldsA0l = &As_lo[32 * wav][0];
    unsigned short* ldsA1l = &As_lo[32 * wav + 16][0];
    unsigned short* ldsBh  = &Bs_hi[16 * wav][0];
    unsigned short* ldsBl  = &Bs_lo[16 * wav][0];

    float4_t acc[2][4];
    #pragma unroll
    for (int mi = 0; mi < 2; ++mi)
        #pragma unroll
        for (int nj = 0; nj < 4; ++nj) acc[mi][nj] = (float4_t)0.f;

    for (int k0 = 0; k0 < Kpad; k0 += KB) {
        __syncthreads();                    // previous tile fully consumed by all waves
        GLDS16(Ah + gA0 + k0, ldsA0h);
        GLDS16(Ah + gA1 + k0, ldsA1h);
        GLDS16(Al + gA0 + k0, ldsA0l);
        GLDS16(Al + gA1 + k0, ldsA1l);
        GLDS16(w_hi + gB + k0, ldsBh);
        GLDS16(w_lo + gB + k0, ldsBl);
        asm volatile("s_waitcnt vmcnt(0)" ::: "memory");   // DMA landed
        __syncthreads();                    // tile visible to all waves

        // A frag: row = 16-block + lr, k = 8*lq + i  (m89/m91-verified 16x16x32 layout)
        short8_t ahf[2], alf[2], bhf[4], blf[4];
        #pragma unroll
        for (int mi = 0; mi < 2; ++mi) {
            int r = wav * 32 + mi * 16 + lr;
            ahf[mi] = *(const short8_t*)&As_hi[r][lq * 8];
            alf[mi] = *(const short8_t*)&As_lo[r][lq * 8];
        }
        #pragma unroll
        for (int nj = 0; nj < 4; ++nj) {
            bhf[nj] = *(const short8_t*)&Bs_hi[nj * 16 + lr][lq * 8];
            blf[nj] = *(const short8_t*)&Bs_lo[nj * 16 + lr][lq * 8];
        }
        #pragma unroll
        for (int mi = 0; mi < 2; ++mi)
            #pragma unroll
            for (int nj = 0; nj < 4; ++nj) {
                acc[mi][nj] = __builtin_amdgcn_mfma_f32_16x16x32_bf16(ahf[mi], bhf[nj], acc[mi][nj], 0, 0, 0);
                acc[mi][nj] = __builtin_amdgcn_mfma_f32_16x16x32_bf16(alf[mi], bhf[nj], acc[mi][nj], 0, 0, 0);
                acc[mi][nj] = __builtin_amdgcn_mfma_f32_16x16x32_bf16(ahf[mi], blf[nj], acc[mi][nj], 0, 0, 0);
            }
    }

    if (!STATS) {
        // C/D map: col = lane&15, row = 4*(lane>>4) + reg  [m89/m91]
        #pragma unroll
        for (int mi = 0; mi < 2; ++mi)
            #pragma unroll
            for (int rr = 0; rr < 4; ++rr) {
                int r = t0 + wav * 32 + mi * 16 + lq * 4 + rr;
                if (r < M) {
                    #pragma unroll
                    for (int nj = 0; nj < 4; ++nj) {
                        int n = n0 + nj * 16 + lr;      // Npad==N==512 for these layers
                        float v = fmaxf(acc[mi][nj][rr] + bias[n], 0.f);
                        unsigned short h = f2bf(v);
                        size_t o = (size_t)b * outB + (size_t)r * N + n;
                        out_hi[o] = h;
                        out_lo[o] = f2bf(v - bf2f(h));
                    }
                }
            }
    } else {
        float cs[4] = {0.f, 0.f, 0.f, 0.f}, cq[4] = {0.f, 0.f, 0.f, 0.f};
        #pragma unroll
        for (int mi = 0; mi < 2; ++mi)
            #pragma unroll
            for (int rr = 0; rr < 4; ++rr) {
                int r = t0 + wav * 32 + mi * 16 + lq * 4 + rr;
                if (r < M) {
                    #pragma unroll
                    for (int nj = 0; nj < 4; ++nj) {
                        int n = n0 + nj * 16 + lr;
                        if (n < N) {                     // Npad=1536 > N=1500 here
                            float v = fmaxf(acc[mi][nj][rr] + bias[n], 0.f);
                            cs[nj] += v;
                            cq[nj] += v * v;
                        }
                    }
                }
            }
        #pragma unroll
        for (int nj = 0; nj < 4; ++nj) {
            cs[nj] += __shfl_xor(cs[nj], 16);
            cs[nj] += __shfl_xor(cs[nj], 32);
            cq[nj] += __shfl_xor(cq[nj], 16);
            cq[nj] += __shfl_xor(cq[nj], 32);
            int n = n0 + nj * 16 + lr;
            if (lq == 0 && n < N) {
                atomicAdd(&gsum[(size_t)b * N + n], cs[nj]);
                atomicAdd(&gsq[(size_t)b * N + n], cq[nj]);
            }
        }
    }
}

// mean/std(ddof=1) -> stats [32][3000] = mean || std
__global__ __launch_bounds__(256) void stats_fin_k(const float* __restrict__ sum,
                                                   const float* __restrict__ sq,
                                                   float* __restrict__ stats) {
    int idx = blockIdx.x * 256 + threadIdx.x;
    if (idx >= NB * TDNN5_) return;
    int b = idx / TDNN5_, c = idx % TDNN5_;
    float s = sum[idx], q = sq[idx];
    float n = (float)T5_;
    float mean = s / n;
    float var = (q - s * s / n) / (n - 1.f);
    stats[(size_t)b * (2 * TDNN5_) + c] = mean;
    stats[(size_t)b * (2 * TDNN5_) + TDNN5_ + c] = sqrtf(fmaxf(var, 0.f));
}

// wave-per-output FC (fp32), K4 = K/4 (all row strides are 16B multiples)
__global__ __launch_bounds__(256) void fc_wave(const float* __restrict__ in,
                                               const float* __restrict__ w,
                                               const float* __restrict__ bias,
                                               float* __restrict__ out,
                                               int Bn, int N, int K4, int doRelu) {
    int wid = blockIdx.x * 4 + (threadIdx.x >> 6);
    int lane = threadIdx.x & 63;
    int b = wid / N, o = wid % N;
    if (b >= Bn) return;
    const float4* xi = (const float4*)(in + (size_t)b * K4 * 4);
    const float4* wi = (const float4*)(w + (size_t)o * K4 * 4);
    float acc = 0.f;
    for (int k = lane; k < K4; k += 64) {
        float4 xv = xi[k], wv = wi[k];
        acc += xv.x * wv.x + xv.y * wv.y + xv.z * wv.z + xv.w * wv.w;
    }
    #pragma unroll
    for (int off = 32; off > 0; off >>= 1) acc += __shfl_down(acc, off);
    if (lane == 0) {
        acc += bias[o];
        if (doRelu) acc = fmaxf(acc, 0.f);
        out[(size_t)b * N + o] = acc;
    }
}

// ---------------- launch ----------------
extern "C" void kernel_launch(void* const* d_in, const int* in_sizes, int n_in,
                              void* d_out, int out_size, void* d_ws, size_t ws_size,
                              hipStream_t stream) {
    const float* x  = (const float*)d_in[0];
    const float* k1 = (const float*)d_in[1];  const float* c1 = (const float*)d_in[2];
    const float* k2 = (const float*)d_in[3];  const float* c2 = (const float*)d_in[4];
    const float* k3 = (const float*)d_in[5];  const float* c3 = (const float*)d_in[6];
    const float* k4 = (const float*)d_in[7];  const float* c4 = (const float*)d_in[8];
    const float* k5 = (const float*)d_in[9];  const float* c5 = (const float*)d_in[10];
    const float* w1 = (const float*)d_in[11]; const float* d1 = (const float*)d_in[12];
    const float* w2 = (const float*)d_in[13]; const float* d2 = (const float*)d_in[14];
    const float* wl = (const float*)d_in[15]; const float* dl = (const float*)d_in[16];

    // ---- workspace layout (byte offsets, 256B aligned) ----
    size_t off = 0;
    auto alloc = [&](size_t bytes) { size_t o = off; off += (bytes + 255) & ~(size_t)255; return o; };
    const size_t ACT_ELEMS = (size_t)NB * T1_ * OUT_DIM_ + 32768;   // + tail-overrun pad
    const size_t oXHI = alloc((size_t)NB * T0_ * IN_DIM_ * 2 + 8192);
    const size_t oXLO = alloc((size_t)NB * T0_ * IN_DIM_ * 2 + 8192);
    const size_t oW1H = alloc((size_t)512 * 224 * 2);
    const size_t oW1L = alloc((size_t)512 * 224 * 2);
    const size_t oW2H = alloc((size_t)512 * 2560 * 2);
    const size_t oW2L = alloc((size_t)512 * 2560 * 2);
    const size_t oW3H = alloc((size_t)512 * 3584 * 2);
    const size_t oW3L = alloc((size_t)512 * 3584 * 2);
    const size_t oW4H = alloc((size_t)512 * 512 * 2);
    const size_t oW4L = alloc((size_t)512 * 512 * 2);
    const size_t oW5H = alloc((size_t)1536 * 512 * 2);
    const size_t oW5L = alloc((size_t)1536 * 512 * 2);
    const size_t oBAH = alloc(ACT_ELEMS * 2);
    const size_t oBAL = alloc(ACT_ELEMS * 2);
    const size_t oBBH = alloc(ACT_ELEMS * 2);
    const size_t oBBL = alloc(ACT_ELEMS * 2);
    const size_t oSUM = alloc((size_t)NB * TDNN5_ * 4);
    const size_t oSQ  = alloc((size_t)NB * TDNN5_ * 4);
    const size_t oST  = alloc((size_t)NB * 2 * TDNN5_ * 4);
    const size_t oE   = alloc((size_t)NB * 512 * 4);
    if (ws_size < off) return;   // insufficient scratch: fail visibly

    char* W = (char*)d_ws;
    unsigned short* xhi = (unsigned short*)(W + oXHI);
    unsigned short* xlo = (unsigned short*)(W + oXLO);
    unsigned short* w1h = (unsigned short*)(W + oW1H);
    unsigned short* w1l = (unsigned short*)(W + oW1L);
    unsigned short* w2h = (unsigned short*)(W + oW2H);
    unsigned short* w2l = (unsigned short*)(W + oW2L);
    unsigned short* w3h = (unsigned short*)(W + oW3H);
    unsigned short* w3l = (unsigned short*)(W + oW3L);
    unsigned short* w4h = (unsigned short*)(W + oW4H);
    unsigned short* w4l = (unsigned short*)(W + oW4L);
    unsigned short* w5h = (unsigned short*)(W + oW5H);
    unsigned short* w5l = (unsigned short*)(W + oW5L);
    unsigned short* bah = (unsigned short*)(W + oBAH);
    unsigned short* bal = (unsigned short*)(W + oBAL);
    unsigned short* bbh = (unsigned short*)(W + oBBH);
    unsigned short* bbl = (unsigned short*)(W + oBBL);
    float* gsum  = (float*)(W + oSUM);
    float* gsq   = (float*)(W + oSQ);
    float* stats = (float*)(W + oST);
    float* evec  = (float*)(W + oE);
    float* emb  = (float*)d_out;
    float* prob = (float*)d_out + NB * 512;

    dim3 blk(256);

    // prep: splits + transposes + zero accumulators
    xsplit_k<<<(NB * T0_ * IN_DIM_ + 255) / 256, blk, 0, stream>>>(x, xhi, xlo);
    wsplit_k<<<(512 * 224 + 255) / 256, blk, 0, stream>>>(k1, w1h, w1l, 512, 512, 200, 224, IN_DIM_, 5);
    wsplit_k<<<(512 * 2560 + 255) / 256, blk, 0, stream>>>(k2, w2h, w2l, 512, 512, 2560, 2560, 512, 5);
    wsplit_k<<<(512 * 3584 + 255) / 256, blk, 0, stream>>>(k3, w3h, w3l, 512, 512, 3584, 3584, 512, 7);
    wsplit_k<<<(512 * 512 + 255) / 256, blk, 0, stream>>>(k4, w4h, w4l, 512, 512, 512, 512, 512, 1);
    wsplit_k<<<(1536 * 512 + 255) / 256, blk, 0, stream>>>(k5, w5h, w5l, 1500, 1536, 512, 512, 512, 1);
    zero_k<<<(2 * NB * TDNN5_ + 255) / 256, blk, 0, stream>>>(gsum, 2 * NB * TDNN5_); // gsum+gsq contiguous

    // conv stack: 1-D grid = GX(8) * GY * NB, y-fastest decode inside kernel
    conv_mfma<false><<<dim3(8 * 8 * NB), blk, 0, stream>>>(
        xhi, xlo, w1h, w1l, c1, bah, bal, nullptr, nullptr,
        8, T1_, 512, 224, IN_DIM_, 0, (long)T0_ * IN_DIM_, (long)T1_ * 512);
    conv_mfma<false><<<dim3(8 * 8 * NB), blk, 0, stream>>>(
        bah, bal, w2h, w2l, c2, bbh, bbl, nullptr, nullptr,
        8, T2_, 512, 2560, 512, 0, (long)T1_ * 512, (long)T2_ * 512);
    conv_mfma<false><<<dim3(8 * 8 * NB), blk, 0, stream>>>(
        bbh, bbl, w3h, w3l, c3, bah, bal, nullptr, nullptr,
        8, T3_, 512, 3584, 512, 0, (long)T2_ * 512, (long)T3_ * 512);
    conv_mfma<false><<<dim3(8 * 8 * NB), blk, 0, stream>>>(
        bah, bal, w4h, w4l, c4, bbh, bbl, nullptr, nullptr,
        8, T4_, 512, 512, 512, 1, (long)T3_ * 512, (long)T4_ * 512);
    conv_mfma<true><<<dim3(8 * 24 * NB), blk, 0, stream>>>(
        bbh, bbl, w5h, w5l, c5, nullptr, nullptr, gsum, gsq,
        24, T5_, TDNN5_, 512, 512, 1, (long)T4_ * 512, 0);

    stats_fin_k<<<(NB * TDNN5_ + 255) / 256, blk, 0, stream>>>(gsum, gsq, stats);

    // FC stack (fp32)
    fc_wave<<<(NB * 512) / 4, blk, 0, stream>>>(stats, w1, d1, evec, NB, 512, 3000 / 4, 1);
    fc_wave<<<(NB * 512) / 4, blk, 0, stream>>>(evec, w2, d2, emb, NB, 512, 512 / 4, 1);
    fc_wave<<<(NB * NCLS_) / 4, blk, 0, stream>>>(emb, wl, dl, prob, NB, NCLS_, 512 / 4, 0);
}

// Round 6
// 1027.233 us; speedup vs baseline: 1.5794x; 1.5794x over previous
//
#include <hip/hip_runtime.h>
#include <hip/hip_bf16.h>

// ---------------- problem constants ----------------
#define NB 32
#define T0_ 1000
#define IN_DIM_ 40
#define OUT_DIM_ 512
#define TDNN5_ 1500
#define T1_ 996
#define T2_ 992
#define T3_ 986
#define T4_ 985
#define T5_ 984
#define NCLS_ 1000

#define TM 128
#define TN 64
#define KB 32

typedef __attribute__((ext_vector_type(8))) short short8_t;   // 8 bf16 = 4 VGPR
typedef __attribute__((ext_vector_type(4))) float float4_t;

// async global->LDS, 16B per lane; LDS dest = wave-uniform base + lane*16 (m104/m108)
#define GLDS16(gp, lp) __builtin_amdgcn_global_load_lds( \
    (__attribute__((address_space(1))) void*)(gp), \
    (__attribute__((address_space(3))) void*)(lp), 16, 0, 0)

__device__ __forceinline__ unsigned short f2bf(float f) {   // RNE f32 -> bf16 bits
    unsigned int u = __float_as_uint(f);
    unsigned int r = u + 0x7FFFu + ((u >> 16) & 1u);
    return (unsigned short)(r >> 16);
}
__device__ __forceinline__ float bf2f(unsigned short h) {
    return __uint_as_float((unsigned int)h << 16);
}

// ---------------- prep kernels ----------------

__global__ __launch_bounds__(256) void xsplit_k(const float* __restrict__ x,
                                                unsigned short* __restrict__ xhi,
                                                unsigned short* __restrict__ xlo) {
    int idx = blockIdx.x * 256 + threadIdx.x;
    if (idx >= NB * T0_ * IN_DIM_) return;
    int i = idx % IN_DIM_;
    int t = (idx / IN_DIM_) % T0_;
    int b = idx / (IN_DIM_ * T0_);
    float v = x[((size_t)b * IN_DIM_ + i) * T0_ + t];
    unsigned short h = f2bf(v);
    xhi[idx] = h;
    xlo[idx] = f2bf(v - bf2f(h));
}

// [Co][Ci][W] f32 -> [Npad][Kpad] bf16 hi/lo, k = w*Ci+i, zero padded
__global__ __launch_bounds__(256) void wsplit_k(const float* __restrict__ src,
                                                unsigned short* __restrict__ whi,
                                                unsigned short* __restrict__ wlo,
                                                int N, int Npad, int K, int Kpad,
                                                int Ci, int W) {
    long total = (long)Npad * Kpad;
    long idx = (long)blockIdx.x * 256 + threadIdx.x;
    if (idx >= total) return;
    int n = (int)(idx / Kpad);
    int k = (int)(idx % Kpad);
    float v = 0.f;
    if (n < N && k < K) {
        int w = k / Ci, i = k % Ci;
        v = src[((size_t)n * Ci + i) * W + w];
    }
    unsigned short h = f2bf(v);
    whi[idx] = h;
    wlo[idx] = f2bf(v - bf2f(h));
}

__global__ __launch_bounds__(256) void zero_k(float* __restrict__ p, int n) {
    int i = blockIdx.x * 256 + threadIdx.x;
    if (i < n) p[i] = 0.f;
}

// ---------------- L1 kernel: round-5 proven conv (Ci=40 path) ----------------
template <bool STATS>
__global__ __launch_bounds__(256, 3) void conv_mfma(
    const unsigned short* __restrict__ in_hi, const unsigned short* __restrict__ in_lo,
    const unsigned short* __restrict__ w_hi,  const unsigned short* __restrict__ w_lo,
    const float* __restrict__ bias,
    unsigned short* __restrict__ out_hi, unsigned short* __restrict__ out_lo,
    float* __restrict__ gsum, float* __restrict__ gsq,
    int GY, int M, int N, int Kpad, int Ci, int rowOff, long inB, long outB) {

    __shared__ unsigned short As_hi[TM][KB];
    __shared__ unsigned short As_lo[TM][KB];
    __shared__ unsigned short Bs_hi[TN][KB];
    __shared__ unsigned short Bs_lo[TN][KB];

    const int tid  = threadIdx.x;
    const int lane = tid & 63;
    const int wav  = tid >> 6;
    const int lr   = lane & 15;
    const int lq   = lane >> 4;

    const int bid = blockIdx.x;
    const int n0 = (bid % GY) * TN;
    const int rem = bid / GY;
    const int t0 = (rem & 7) * TM;
    const int b  = rem >> 3;

    const int sr = lane >> 2;
    const int sc = (lane & 3) * 8;
    const unsigned short* Ah = in_hi + (size_t)b * inB;
    const unsigned short* Al = in_lo + (size_t)b * inB;
    const size_t gA0 = (size_t)(t0 + rowOff + 32 * wav + sr) * Ci + sc;
    const size_t gA1 = (size_t)(t0 + rowOff + 32 * wav + 16 + sr) * Ci + sc;
    const size_t gB  = (size_t)(n0 + 16 * wav + sr) * Kpad + sc;
    unsigned short* ldsA0h = &As_hi[32 * wav][0];
    unsigned short* ldsA1h = &As_hi[32 * wav + 16][0];
    unsigned short* ldsA0l = &As_lo[32 * wav][0];
    unsigned short* ldsA1l = &As_lo[32 * wav + 16][0];
    unsigned short* ldsBh  = &Bs_hi[16 * wav][0];
    unsigned short* ldsBl  = &Bs_lo[16 * wav][0];

    float4_t acc[2][4];
    #pragma unroll
    for (int mi = 0; mi < 2; ++mi)
        #pragma unroll
        for (int nj = 0; nj < 4; ++nj) acc[mi][nj] = (float4_t)0.f;

    for (int k0 = 0; k0 < Kpad; k0 += KB) {
        __syncthreads();
        GLDS16(Ah + gA0 + k0, ldsA0h);
        GLDS16(Ah + gA1 + k0, ldsA1h);
        GLDS16(Al + gA0 + k0, ldsA0l);
        GLDS16(Al + gA1 + k0, ldsA1l);
        GLDS16(w_hi + gB + k0, ldsBh);
        GLDS16(w_lo + gB + k0, ldsBl);
        asm volatile("s_waitcnt vmcnt(0)" ::: "memory");
        __syncthreads();

        short8_t ahf[2], alf[2], bhf[4], blf[4];
        #pragma unroll
        for (int mi = 0; mi < 2; ++mi) {
            int r = wav * 32 + mi * 16 + lr;
            ahf[mi] = *(const short8_t*)&As_hi[r][lq * 8];
            alf[mi] = *(const short8_t*)&As_lo[r][lq * 8];
        }
        #pragma unroll
        for (int nj = 0; nj < 4; ++nj) {
            bhf[nj] = *(const short8_t*)&Bs_hi[nj * 16 + lr][lq * 8];
            blf[nj] = *(const short8_t*)&Bs_lo[nj * 16 + lr][lq * 8];
        }
        #pragma unroll
        for (int mi = 0; mi < 2; ++mi)
            #pragma unroll
            for (int nj = 0; nj < 4; ++nj) {
                acc[mi][nj] = __builtin_amdgcn_mfma_f32_16x16x32_bf16(ahf[mi], bhf[nj], acc[mi][nj], 0, 0, 0);
                acc[mi][nj] = __builtin_amdgcn_mfma_f32_16x16x32_bf16(alf[mi], bhf[nj], acc[mi][nj], 0, 0, 0);
                acc[mi][nj] = __builtin_amdgcn_mfma_f32_16x16x32_bf16(ahf[mi], blf[nj], acc[mi][nj], 0, 0, 0);
            }
    }

    if (!STATS) {
        #pragma unroll
        for (int mi = 0; mi < 2; ++mi)
            #pragma unroll
            for (int rr = 0; rr < 4; ++rr) {
                int r = t0 + wav * 32 + mi * 16 + lq * 4 + rr;
                if (r < M) {
                    #pragma unroll
                    for (int nj = 0; nj < 4; ++nj) {
                        int n = n0 + nj * 16 + lr;
                        float v = fmaxf(acc[mi][nj][rr] + bias[n], 0.f);
                        unsigned short h = f2bf(v);
                        size_t o = (size_t)b * outB + (size_t)r * N + n;
                        out_hi[o] = h;
                        out_lo[o] = f2bf(v - bf2f(h));
                    }
                }
            }
    } else {
        float cs[4] = {0.f, 0.f, 0.f, 0.f}, cq[4] = {0.f, 0.f, 0.f, 0.f};
        #pragma unroll
        for (int mi = 0; mi < 2; ++mi)
            #pragma unroll
            for (int rr = 0; rr < 4; ++rr) {
                int r = t0 + wav * 32 + mi * 16 + lq * 4 + rr;
                if (r < M) {
                    #pragma unroll
                    for (int nj = 0; nj < 4; ++nj) {
                        int n = n0 + nj * 16 + lr;
                        if (n < N) {
                            float v = fmaxf(acc[mi][nj][rr] + bias[n], 0.f);
                            cs[nj] += v;
                            cq[nj] += v * v;
                        }
                    }
                }
            }
        #pragma unroll
        for (int nj = 0; nj < 4; ++nj) {
            cs[nj] += __shfl_xor(cs[nj], 16);
            cs[nj] += __shfl_xor(cs[nj], 32);
            cq[nj] += __shfl_xor(cq[nj], 16);
            cq[nj] += __shfl_xor(cq[nj], 32);
            int n = n0 + nj * 16 + lr;
            if (lq == 0 && n < N) {
                atomicAdd(&gsum[(size_t)b * N + n], cs[nj]);
                atomicAdd(&gsq[(size_t)b * N + n], cq[nj]);
            }
        }
    }
}

// ---------------- tap-aware conv for L2-L5 (Ci=512, TM=256) ----------------
// K = TAPS*512; k = w*512 + c.  Stage raw act window [272 rows][32 ch] once per
// channel-block (shared by all taps -> A traffic /TAPS), loop taps staging only
// the 64x32 B-slice.  4 waves, each owns 64 output rows (4x4 16x16 frags).
// Split-bf16: 3 MFMAs (hh, lh, hl).  Grid 1-D: GX=4 x-tiles, y-fastest (XCD pin).
#define AROWS 272
template <int TAPS, bool STATS>
__global__ __launch_bounds__(256, 3) void conv_tap(
    const unsigned short* __restrict__ in_hi, const unsigned short* __restrict__ in_lo,
    const unsigned short* __restrict__ w_hi,  const unsigned short* __restrict__ w_lo,
    const float* __restrict__ bias,
    unsigned short* __restrict__ out_hi, unsigned short* __restrict__ out_lo,
    float* __restrict__ gsum, float* __restrict__ gsq,
    int GY, int M, int N, int rowOff, long inB, long outB) {

    __shared__ unsigned short Ah_s[AROWS * 32];   // act rows t0+rowOff+0..271, 64B rows
    __shared__ unsigned short Al_s[AROWS * 32];
    __shared__ unsigned short Bh_s[TN * 32];      // 64 n-rows x 32 k
    __shared__ unsigned short Bl_s[TN * 32];

    const int tid  = threadIdx.x;
    const int lane = tid & 63;
    const int wav  = tid >> 6;
    const int lr   = lane & 15;
    const int lq   = lane >> 4;
    const int KSTR = TAPS * 512;                  // weight row stride

    const int bid = blockIdx.x;
    const int n0 = (bid % GY) * TN;
    const int rem = bid / GY;
    const int t0 = (rem & 3) * 256;               // GX = 4
    const int b  = rem >> 2;

    // staging coords: chunk = 16B; act chunk c -> row c>>2, slot c&3 (4 chunks/64B row)
    const int arow = tid >> 2;                    // wav*16 + lane>>2
    const int acol = (tid & 3) * 8;
    const unsigned short* Agh = in_hi + (size_t)b * inB + (size_t)(t0 + rowOff) * 512;
    const unsigned short* Agl = in_lo + (size_t)b * inB + (size_t)(t0 + rowOff) * 512;
    const size_t bsrc0 = (size_t)(n0 + (tid >> 2)) * KSTR + acol;   // B: 256 chunks exactly
    unsigned short* dB_h = Bh_s + wav * 512;      // wave-uniform dest (64 chunks/wave)
    unsigned short* dB_l = Bl_s + wav * 512;

    float4_t acc[4][4];
    #pragma unroll
    for (int mi = 0; mi < 4; ++mi)
        #pragma unroll
        for (int nj = 0; nj < 4; ++nj) acc[mi][nj] = (float4_t)0.f;

    for (int c32 = 0; c32 < 16; ++c32) {
        const int cc = c32 * 32;
        // ---- stage act window (both planes): 1088 chunks = 4 full rounds + wave-0 round
        #pragma unroll
        for (int q = 0; q < 4; ++q) {
            size_t aoff = (size_t)(q * 64 + arow) * 512 + cc + acol;
            GLDS16(Agh + aoff, Ah_s + (q * 256 + wav * 64) * 8);
            GLDS16(Agl + aoff, Al_s + (q * 256 + wav * 64) * 8);
        }
        if (wav == 0) {   // rows 256..271 (chunks 1024..1087) — wave-uniform branch
            size_t aoff = (size_t)(256 + (lane >> 2)) * 512 + cc + (lane & 3) * 8;
            GLDS16(Agh + aoff, Ah_s + 1024 * 8);
            GLDS16(Agl + aoff, Al_s + 1024 * 8);
        }
        #pragma unroll
        for (int w = 0; w < TAPS; ++w) {
            // ---- stage B slice (w, c32): 64 rows x 32 k, 256 chunks
            GLDS16(w_hi + bsrc0 + w * 512 + cc, dB_h);
            GLDS16(w_lo + bsrc0 + w * 512 + cc, dB_l);
            asm volatile("s_waitcnt vmcnt(0)" ::: "memory");
            __syncthreads();
            // ---- fragments; A rows shifted by tap w
            short8_t ahf[4], alf[4], bhf[4], blf[4];
            #pragma unroll
            for (int mi = 0; mi < 4; ++mi) {
                int r = wav * 64 + mi * 16 + lr + w;
                ahf[mi] = *(const short8_t*)&Ah_s[r * 32 + lq * 8];
                alf[mi] = *(const short8_t*)&Al_s[r * 32 + lq * 8];
            }
            #pragma unroll
            for (int nj = 0; nj < 4; ++nj) {
                bhf[nj] = *(const short8_t*)&Bh_s[(nj * 16 + lr) * 32 + lq * 8];
                blf[nj] = *(const short8_t*)&Bl_s[(nj * 16 + lr) * 32 + lq * 8];
            }
            #pragma unroll
            for (int mi = 0; mi < 4; ++mi)
                #pragma unroll
                for (int nj = 0; nj < 4; ++nj) {
                    acc[mi][nj] = __builtin_amdgcn_mfma_f32_16x16x32_bf16(ahf[mi], bhf[nj], acc[mi][nj], 0, 0, 0);
                    acc[mi][nj] = __builtin_amdgcn_mfma_f32_16x16x32_bf16(alf[mi], bhf[nj], acc[mi][nj], 0, 0, 0);
                    acc[mi][nj] = __builtin_amdgcn_mfma_f32_16x16x32_bf16(ahf[mi], blf[nj], acc[mi][nj], 0, 0, 0);
                }
            __syncthreads();   // frags consumed; B (and act at tap end) may be overwritten
        }
    }

    if (!STATS) {
        #pragma unroll
        for (int mi = 0; mi < 4; ++mi)
            #pragma unroll
            for (int rr = 0; rr < 4; ++rr) {
                int r = t0 + wav * 64 + mi * 16 + lq * 4 + rr;
                if (r < M) {
                    #pragma unroll
                    for (int nj = 0; nj < 4; ++nj) {
                        int n = n0 + nj * 16 + lr;
                        float v = fmaxf(acc[mi][nj][rr] + bias[n], 0.f);
                        unsigned short h = f2bf(v);
                        size_t o = (size_t)b * outB + (size_t)r * N + n;
                        out_hi[o] = h;
                        out_lo[o] = f2bf(v - bf2f(h));
                    }
                }
            }
    } else {
        float cs[4] = {0.f, 0.f, 0.f, 0.f}, cq[4] = {0.f, 0.f, 0.f, 0.f};
        #pragma unroll
        for (int mi = 0; mi < 4; ++mi)
            #pragma unroll
            for (int rr = 0; rr < 4; ++rr) {
                int r = t0 + wav * 64 + mi * 16 + lq * 4 + rr;
                if (r < M) {
                    #pragma unroll
                    for (int nj = 0; nj < 4; ++nj) {
                        int n = n0 + nj * 16 + lr;
                        if (n < N) {
                            float v = fmaxf(acc[mi][nj][rr] + bias[n], 0.f);
                            cs[nj] += v;
                            cq[nj] += v * v;
                        }
                    }
                }
            }
        #pragma unroll
        for (int nj = 0; nj < 4; ++nj) {
            cs[nj] += __shfl_xor(cs[nj], 16);
            cs[nj] += __shfl_xor(cs[nj], 32);
            cq[nj] += __shfl_xor(cq[nj], 16);
            cq[nj] += __shfl_xor(cq[nj], 32);
            int n = n0 + nj * 16 + lr;
            if (lq == 0 && n < N) {
                atomicAdd(&gsum[(size_t)b * N + n], cs[nj]);
                atomicAdd(&gsq[(size_t)b * N + n], cq[nj]);
            }
        }
    }
}

// mean/std(ddof=1) -> stats [32][3000]
__global__ __launch_bounds__(256) void stats_fin_k(const float* __restrict__ sum,
                                                   const float* __restrict__ sq,
                                                   float* __restrict__ stats) {
    int idx = blockIdx.x * 256 + threadIdx.x;
    if (idx >= NB * TDNN5_) return;
    int b = idx / TDNN5_, c = idx % TDNN5_;
    float s = sum[idx], q = sq[idx];
    float n = (float)T5_;
    float mean = s / n;
    float var = (q - s * s / n) / (n - 1.f);
    stats[(size_t)b * (2 * TDNN5_) + c] = mean;
    stats[(size_t)b * (2 * TDNN5_) + TDNN5_ + c] = sqrtf(fmaxf(var, 0.f));
}

// wave-per-output FC (fp32)
__global__ __launch_bounds__(256) void fc_wave(const float* __restrict__ in,
                                               const float* __restrict__ w,
                                               const float* __restrict__ bias,
                                               float* __restrict__ out,
                                               int Bn, int N, int K4, int doRelu) {
    int wid = blockIdx.x * 4 + (threadIdx.x >> 6);
    int lane = threadIdx.x & 63;
    int b = wid / N, o = wid % N;
    if (b >= Bn) return;
    const float4* xi = (const float4*)(in + (size_t)b * K4 * 4);
    const float4* wi = (const float4*)(w + (size_t)o * K4 * 4);
    float acc = 0.f;
    for (int k = lane; k < K4; k += 64) {
        float4 xv = xi[k], wv = wi[k];
        acc += xv.x * wv.x + xv.y * wv.y + xv.z * wv.z + xv.w * wv.w;
    }
    #pragma unroll
    for (int off = 32; off > 0; off >>= 1) acc += __shfl_down(acc, off);
    if (lane == 0) {
        acc += bias[o];
        if (doRelu) acc = fmaxf(acc, 0.f);
        out[(size_t)b * N + o] = acc;
    }
}

// ---------------- launch ----------------
extern "C" void kernel_launch(void* const* d_in, const int* in_sizes, int n_in,
                              void* d_out, int out_size, void* d_ws, size_t ws_size,
                              hipStream_t stream) {
    const float* x  = (const float*)d_in[0];
    const float* k1 = (const float*)d_in[1];  const float* c1 = (const float*)d_in[2];
    const float* k2 = (const float*)d_in[3];  const float* c2 = (const float*)d_in[4];
    const float* k3 = (const float*)d_in[5];  const float* c3 = (const float*)d_in[6];
    const float* k4 = (const float*)d_in[7];  const float* c4 = (const float*)d_in[8];
    const float* k5 = (const float*)d_in[9];  const float* c5 = (const float*)d_in[10];
    const float* w1 = (const float*)d_in[11]; const float* d1 = (const float*)d_in[12];
    const float* w2 = (const float*)d_in[13]; const float* d2 = (const float*)d_in[14];
    const float* wl = (const float*)d_in[15]; const float* dl = (const float*)d_in[16];

    size_t off = 0;
    auto alloc = [&](size_t bytes) { size_t o = off; off += (bytes + 255) & ~(size_t)255; return o; };
    const size_t ACT_ELEMS = (size_t)NB * T1_ * OUT_DIM_ + 32768;
    const size_t oXHI = alloc((size_t)NB * T0_ * IN_DIM_ * 2 + 8192);
    const size_t oXLO = alloc((size_t)NB * T0_ * IN_DIM_ * 2 + 8192);
    const size_t oW1H = alloc((size_t)512 * 224 * 2 + 256);
    const size_t oW1L = alloc((size_t)512 * 224 * 2 + 256);
    const size_t oW2H = alloc((size_t)512 * 2560 * 2 + 256);
    const size_t oW2L = alloc((size_t)512 * 2560 * 2 + 256);
    const size_t oW3H = alloc((size_t)512 * 3584 * 2 + 256);
    const size_t oW3L = alloc((size_t)512 * 3584 * 2 + 256);
    const size_t oW4H = alloc((size_t)512 * 512 * 2 + 256);
    const size_t oW4L = alloc((size_t)512 * 512 * 2 + 256);
    const size_t oW5H = alloc((size_t)1536 * 512 * 2 + 256);
    const size_t oW5L = alloc((size_t)1536 * 512 * 2 + 256);
    const size_t oBAH = alloc(ACT_ELEMS * 2);
    const size_t oBAL = alloc(ACT_ELEMS * 2);
    const size_t oBBH = alloc(ACT_ELEMS * 2);
    const size_t oBBL = alloc(ACT_ELEMS * 2);
    const size_t oSUM = alloc((size_t)NB * TDNN5_ * 4);
    const size_t oSQ  = alloc((size_t)NB * TDNN5_ * 4);
    const size_t oST  = alloc((size_t)NB * 2 * TDNN5_ * 4);
    const size_t oE   = alloc((size_t)NB * 512 * 4);
    if (ws_size < off) return;

    char* W = (char*)d_ws;
    unsigned short* xhi = (unsigned short*)(W + oXHI);
    unsigned short* xlo = (unsigned short*)(W + oXLO);
    unsigned short* w1h = (unsigned short*)(W + oW1H);
    unsigned short* w1l = (unsigned short*)(W + oW1L);
    unsigned short* w2h = (unsigned short*)(W + oW2H);
    unsigned short* w2l = (unsigned short*)(W + oW2L);
    unsigned short* w3h = (unsigned short*)(W + oW3H);
    unsigned short* w3l = (unsigned short*)(W + oW3L);
    unsigned short* w4h = (unsigned short*)(W + oW4H);
    unsigned short* w4l = (unsigned short*)(W + oW4L);
    unsigned short* w5h = (unsigned short*)(W + oW5H);
    unsigned short* w5l = (unsigned short*)(W + oW5L);
    unsigned short* bah = (unsigned short*)(W + oBAH);
    unsigned short* bal = (unsigned short*)(W + oBAL);
    unsigned short* bbh = (unsigned short*)(W + oBBH);
    unsigned short* bbl = (unsigned short*)(W + oBBL);
    float* gsum  = (float*)(W + oSUM);
    float* gsq   = (float*)(W + oSQ);
    float* stats = (float*)(W + oST);
    float* evec  = (float*)(W + oE);
    float* emb  = (float*)d_out;
    float* prob = (float*)d_out + NB * 512;

    dim3 blk(256);

    xsplit_k<<<(NB * T0_ * IN_DIM_ + 255) / 256, blk, 0, stream>>>(x, xhi, xlo);
    wsplit_k<<<(512 * 224 + 255) / 256, blk, 0, stream>>>(k1, w1h, w1l, 512, 512, 200, 224, IN_DIM_, 5);
    wsplit_k<<<(512 * 2560 + 255) / 256, blk, 0, stream>>>(k2, w2h, w2l, 512, 512, 2560, 2560, 512, 5);
    wsplit_k<<<(512 * 3584 + 255) / 256, blk, 0, stream>>>(k3, w3h, w3l, 512, 512, 3584, 3584, 512, 7);
    wsplit_k<<<(512 * 512 + 255) / 256, blk, 0, stream>>>(k4, w4h, w4l, 512, 512, 512, 512, 512, 1);
    wsplit_k<<<(1536 * 512 + 255) / 256, blk, 0, stream>>>(k5, w5h, w5l, 1500, 1536, 512, 512, 512, 1);
    zero_k<<<(2 * NB * TDNN5_ + 255) / 256, blk, 0, stream>>>(gsum, 2 * NB * TDNN5_);

    // L1: proven 128-tile kernel (Ci=40).  grid = 8x8x32, y-fastest
    conv_mfma<false><<<dim3(8 * 8 * NB), blk, 0, stream>>>(
        xhi, xlo, w1h, w1l, c1, bah, bal, nullptr, nullptr,
        8, T1_, 512, 224, IN_DIM_, 0, (long)T0_ * IN_DIM_, (long)T1_ * 512);
    // L2-L5: tap-aware TM=256 kernel.  grid = GX(4) * GY * NB, y-fastest
    conv_tap<5, false><<<dim3(4 * 8 * NB), blk, 0, stream>>>(
        bah, bal, w2h, w2l, c2, bbh, bbl, nullptr, nullptr,
        8, T2_, 512, 0, (long)T1_ * 512, (long)T2_ * 512);
    conv_tap<7, false><<<dim3(4 * 8 * NB), blk, 0, stream>>>(
        bbh, bbl, w3h, w3l, c3, bah, bal, nullptr, nullptr,
        8, T3_, 512, 0, (long)T2_ * 512, (long)T3_ * 512);
    conv_tap<1, false><<<dim3(4 * 8 * NB), blk, 0, stream>>>(
        bah, bal, w4h, w4l, c4, bbh, bbl, nullptr, nullptr,
        8, T4_, 512, 1, (long)T3_ * 512, (long)T4_ * 512);
    conv_tap<1, true><<<dim3(4 * 24 * NB), blk, 0, stream>>>(
        bbh, bbl, w5h, w5l, c5, nullptr, nullptr, gsum, gsq,
        24, T5_, TDNN5_, 1, (long)T4_ * 512, 0);

    stats_fin_k<<<(NB * TDNN5_ + 255) / 256, blk, 0, stream>>>(gsum, gsq, stats);

    fc_wave<<<(NB * 512) / 4, blk, 0, stream>>>(stats, w1, d1, evec, NB, 512, 3000 / 4, 1);
    fc_wave<<<(NB * 512) / 4, blk, 0, stream>>>(evec, w2, d2, emb, NB, 512, 512 / 4, 1);
    fc_wave<<<(NB * NCLS_) / 4, blk, 0, stream>>>(emb, wl, dl, prob, NB, NCLS_, 512 / 4, 0);
}